// Round 1
// baseline (544.156 us; speedup 1.0000x reference)
//
#include <hip/hip_runtime.h>
#include <math.h>

#define BATCH 64
#define IN_DIM 512
#define MEM 1024

// ---------------------------------------------------------------------------
// Kernel 1: gates. out[g][b][m] = act_g( sum_k x[b,k]*W_g[m,k] + bias_g[m] )
// grid 192 x 256. Each wave handles 8 consecutive output columns (gm), lane=b.
// x chunk staged TRANSPOSED in LDS -> conflict-free column reads
// (bank = (k + lane) % 32, 2-way aliasing which is free on CDNA4).
// W reads are wave-uniform -> scalar loads (s_load_dwordx4).
// ---------------------------------------------------------------------------
__global__ __launch_bounds__(256)
void gates_kernel(const float* __restrict__ x,
                  const float* __restrict__ Wq, const float* __restrict__ bq,
                  const float* __restrict__ Wk, const float* __restrict__ bk,
                  const float* __restrict__ Wv, const float* __restrict__ bv,
                  const float* __restrict__ Wi, const float* __restrict__ bi,
                  const float* __restrict__ Wf, const float* __restrict__ bf,
                  const float* __restrict__ Wo, const float* __restrict__ bo,
                  float* __restrict__ gates /* [6][BATCH][MEM] */) {
    __shared__ float xs[64][65];   // xs[k_local][b], pad 65 -> bank (k+b)%32
    const int t    = threadIdx.x;
    const int lane = t & 63;                                    // = batch b
    const int wave = __builtin_amdgcn_readfirstlane(t >> 6);    // SGPR
    const int gm0  = blockIdx.x * 32 + wave * 8;                // col base
    const int g    = gm0 >> 10;                                 // gate id
    const int m0   = gm0 & 1023;

    const float* W; const float* bias;
    switch (g) {
        case 0: W = Wq; bias = bq; break;
        case 1: W = Wk; bias = bk; break;
        case 2: W = Wv; bias = bv; break;
        case 3: W = Wi; bias = bi; break;
        case 4: W = Wf; bias = bf; break;
        default: W = Wo; bias = bo; break;
    }

    float acc[8];
#pragma unroll
    for (int j = 0; j < 8; ++j) acc[j] = 0.f;

    for (int kk = 0; kk < IN_DIM; kk += 64) {
        __syncthreads();
        // cooperative load of x[:, kk:kk+64], transposed into LDS
#pragma unroll
        for (int j = 0; j < 4; ++j) {
            int ii = t + j * 256;          // 1024 float4 total
            int bb = ii >> 4;              // batch row
            int c4 = ii & 15;              // float4 within chunk
            float4 v = *(const float4*)&x[bb * IN_DIM + kk + c4 * 4];
            xs[c4 * 4 + 0][bb] = v.x;
            xs[c4 * 4 + 1][bb] = v.y;
            xs[c4 * 4 + 2][bb] = v.z;
            xs[c4 * 4 + 3][bb] = v.w;
        }
        __syncthreads();

        const float* wp = W + (size_t)m0 * IN_DIM + kk;
#pragma unroll 4
        for (int k4 = 0; k4 < 16; ++k4) {
            float4 wv[8];
#pragma unroll
            for (int j = 0; j < 8; ++j)
                wv[j] = *(const float4*)(wp + j * IN_DIM + k4 * 4);
            float x0 = xs[k4 * 4 + 0][lane];
            float x1 = xs[k4 * 4 + 1][lane];
            float x2 = xs[k4 * 4 + 2][lane];
            float x3 = xs[k4 * 4 + 3][lane];
#pragma unroll
            for (int j = 0; j < 8; ++j) {
                acc[j] += x0 * wv[j].x;
                acc[j] += x1 * wv[j].y;
                acc[j] += x2 * wv[j].z;
                acc[j] += x3 * wv[j].w;
            }
        }
    }

    // epilogue: bias + activation, store [g][b=lane][m0..m0+7] as 2 float4
    float v[8];
#pragma unroll
    for (int j = 0; j < 8; ++j) {
        float val = acc[j] + bias[m0 + j];
        if (g == 1)      val *= 0.03125f;                 // k / sqrt(M)
        else if (g == 3) val = __expf(val);               // exponential gate i
        else if (g >= 4) val = 1.f / (1.f + __expf(-val)); // sigmoid f, o
        v[j] = val;
    }
    float* outp = gates + (size_t)g * BATCH * MEM + (size_t)lane * MEM + m0;
    *(float4*)(outp + 0) = make_float4(v[0], v[1], v[2], v[3]);
    *(float4*)(outp + 4) = make_float4(v[4], v[5], v[6], v[7]);
}

// ---------------------------------------------------------------------------
// Kernel 2: n_t = f*n_prev + i*k ; denom[b] = max(n_t . q, 1)
// grid 64 (one block per batch) x 256
// ---------------------------------------------------------------------------
__global__ __launch_bounds__(256)
void nt_denom_kernel(const float* __restrict__ gates,
                     const float* __restrict__ n_prev,
                     float* __restrict__ n_out,
                     float* __restrict__ denom) {
    const int b = blockIdx.x;
    const int t = threadIdx.x;
    const float* q  = gates + 0 * BATCH * MEM + (size_t)b * MEM;
    const float* k  = gates + 1 * BATCH * MEM + (size_t)b * MEM;
    const float* ig = gates + 3 * BATCH * MEM + (size_t)b * MEM;
    const float* fg = gates + 4 * BATCH * MEM + (size_t)b * MEM;

    float part = 0.f;
#pragma unroll
    for (int j = 0; j < 4; ++j) {
        int m = t + j * 256;
        float nt = fg[m] * n_prev[(size_t)b * MEM + m] + ig[m] * k[m];
        n_out[(size_t)b * MEM + m] = nt;
        part += nt * q[m];
    }
#pragma unroll
    for (int off = 32; off; off >>= 1) part += __shfl_xor(part, off, 64);

    __shared__ float red[4];
    if ((t & 63) == 0) red[t >> 6] = part;
    __syncthreads();
    if (t == 0) denom[b] = fmaxf(red[0] + red[1] + red[2] + red[3], 1.0f);
}

// ---------------------------------------------------------------------------
// Kernel 3 (the roofline): per C-row (b,m):
//   C_t[b,m,:] = f[b,m]*C_prev[b,m,:] + (i*v)[b,m]*k[b,:]
//   h_t[b,m]   = o[b,m] * (C_t[b,m,:] . q[b,:]) / denom[b]
// One wave per row; q,k staged in LDS; float4 coalesced streams.
// grid 16384 x 256 (4 waves = 4 rows per block, never crossing b).
// ---------------------------------------------------------------------------
__global__ __launch_bounds__(256)
void update_kernel(const float* __restrict__ C_prev,
                   const float* __restrict__ gates,
                   const float* __restrict__ denom,
                   float* __restrict__ h_out,
                   float* __restrict__ C_out) {
    __shared__ float4 qs[MEM / 4];
    __shared__ float4 ks[MEM / 4];
    const int t    = threadIdx.x;
    const int row0 = blockIdx.x * 4;
    const int b    = row0 >> 10;

    qs[t] = ((const float4*)(gates + 0 * BATCH * MEM + (size_t)b * MEM))[t];
    ks[t] = ((const float4*)(gates + 1 * BATCH * MEM + (size_t)b * MEM))[t];
    __syncthreads();

    const int wave = __builtin_amdgcn_readfirstlane(t >> 6);
    const int lane = t & 63;
    const int row  = row0 + wave;
    const int m    = row & 1023;

    const float fm = gates[4 * BATCH * MEM + (size_t)b * MEM + m];
    const float iv = gates[3 * BATCH * MEM + (size_t)b * MEM + m] *
                     gates[2 * BATCH * MEM + (size_t)b * MEM + m];
    const float om = gates[5 * BATCH * MEM + (size_t)b * MEM + m];

    const float4* cp = (const float4*)(C_prev + (size_t)row * MEM);
    float4*       co = (float4*)(C_out + (size_t)row * MEM);

    float acc = 0.f;
#pragma unroll
    for (int c = 0; c < 4; ++c) {
        int n4 = c * 64 + lane;
        float4 cv = cp[n4];
        float4 kv = ks[n4];
        float4 qv = qs[n4];
        float4 ct;
        ct.x = fm * cv.x + iv * kv.x;
        ct.y = fm * cv.y + iv * kv.y;
        ct.z = fm * cv.z + iv * kv.z;
        ct.w = fm * cv.w + iv * kv.w;
        co[n4] = ct;
        acc += ct.x * qv.x + ct.y * qv.y + ct.z * qv.z + ct.w * qv.w;
    }
#pragma unroll
    for (int off = 32; off; off >>= 1) acc += __shfl_xor(acc, off, 64);

    if (lane == 0) h_out[row] = om * acc / denom[b];
}

// ---------------------------------------------------------------------------
extern "C" void kernel_launch(void* const* d_in, const int* in_sizes, int n_in,
                              void* d_out, int out_size, void* d_ws, size_t ws_size,
                              hipStream_t stream) {
    const float* x      = (const float*)d_in[0];
    // d_in[1]=h_prev, d_in[2]=c_prev unused (pass-through in reference)
    const float* C_prev = (const float*)d_in[3];
    const float* n_prev = (const float*)d_in[4];
    // d_in[5]=m_prev unused
    const float* Wq = (const float*)d_in[6];  const float* bq = (const float*)d_in[7];
    const float* Wk = (const float*)d_in[8];  const float* bk = (const float*)d_in[9];
    const float* Wv = (const float*)d_in[10]; const float* bv = (const float*)d_in[11];
    const float* Wi = (const float*)d_in[12]; const float* bi = (const float*)d_in[13];
    const float* Wf = (const float*)d_in[14]; const float* bf = (const float*)d_in[15];
    const float* Wo = (const float*)d_in[16]; const float* bo = (const float*)d_in[17];

    float* h_out = (float*)d_out;                       // [64,1024]
    float* C_out = h_out + BATCH * MEM;                 // [64,1024,1024]
    float* n_out = C_out + (size_t)BATCH * MEM * MEM;   // [64,1024]

    float* gates = (float*)d_ws;                        // 6 * 64 * 1024 floats
    float* denom = gates + 6 * BATCH * MEM;             // 64 floats

    gates_kernel<<<192, 256, 0, stream>>>(x, Wq, bq, Wk, bk, Wv, bv,
                                          Wi, bi, Wf, bf, Wo, bo, gates);
    nt_denom_kernel<<<64, 256, 0, stream>>>(gates, n_prev, n_out, denom);
    update_kernel<<<16384, 256, 0, stream>>>(C_prev, gates, denom, h_out, C_out);
}

// Round 2
// 507.221 us; speedup vs baseline: 1.0728x; 1.0728x over previous
//
#include <hip/hip_runtime.h>
#include <math.h>

#define BATCH 64
#define IN_DIM 512
#define MEM 1024

typedef float f32x4 __attribute__((ext_vector_type(4)));

// ---------------------------------------------------------------------------
// Kernel 1: gates. out[g][b][m] = act_g( sum_k x[b,k]*W_g[m,k] + bias_g[m] )
// grid 192 x 256. Each wave handles 8 consecutive output columns (gm), lane=b.
// x chunk staged TRANSPOSED in LDS; W rows via wave-uniform (scalar) loads.
// unroll 2 (was 4): keep live W registers <= 64 to avoid spill.
// ---------------------------------------------------------------------------
__global__ __launch_bounds__(256)
void gates_kernel(const float* __restrict__ x,
                  const float* __restrict__ Wq, const float* __restrict__ bq,
                  const float* __restrict__ Wk, const float* __restrict__ bk,
                  const float* __restrict__ Wv, const float* __restrict__ bv,
                  const float* __restrict__ Wi, const float* __restrict__ bi,
                  const float* __restrict__ Wf, const float* __restrict__ bf,
                  const float* __restrict__ Wo, const float* __restrict__ bo,
                  float* __restrict__ gates /* [6][BATCH][MEM] */) {
    __shared__ float xs[64][65];   // xs[k_local][b]
    const int t    = threadIdx.x;
    const int lane = t & 63;                                    // = batch b
    const int wave = __builtin_amdgcn_readfirstlane(t >> 6);    // SGPR
    const int gm0  = blockIdx.x * 32 + wave * 8;                // col base
    const int g    = gm0 >> 10;                                 // gate id
    const int m0   = gm0 & 1023;

    const float* W; const float* bias;
    switch (g) {
        case 0: W = Wq; bias = bq; break;
        case 1: W = Wk; bias = bk; break;
        case 2: W = Wv; bias = bv; break;
        case 3: W = Wi; bias = bi; break;
        case 4: W = Wf; bias = bf; break;
        default: W = Wo; bias = bo; break;
    }

    float acc[8];
#pragma unroll
    for (int j = 0; j < 8; ++j) acc[j] = 0.f;

    for (int kk = 0; kk < IN_DIM; kk += 64) {
        __syncthreads();
        // cooperative load of x[:, kk:kk+64], transposed into LDS
#pragma unroll
        for (int j = 0; j < 4; ++j) {
            int ii = t + j * 256;          // 1024 float4 total
            int bb = ii >> 4;              // batch row
            int c4 = ii & 15;              // float4 within chunk
            float4 v = *(const float4*)&x[bb * IN_DIM + kk + c4 * 4];
            xs[c4 * 4 + 0][bb] = v.x;
            xs[c4 * 4 + 1][bb] = v.y;
            xs[c4 * 4 + 2][bb] = v.z;
            xs[c4 * 4 + 3][bb] = v.w;
        }
        __syncthreads();

        const float* wp = W + (size_t)m0 * IN_DIM + kk;
#pragma unroll 2
        for (int k4 = 0; k4 < 16; ++k4) {
            float4 wv[8];
#pragma unroll
            for (int j = 0; j < 8; ++j)
                wv[j] = *(const float4*)(wp + j * IN_DIM + k4 * 4);
            float x0 = xs[k4 * 4 + 0][lane];
            float x1 = xs[k4 * 4 + 1][lane];
            float x2 = xs[k4 * 4 + 2][lane];
            float x3 = xs[k4 * 4 + 3][lane];
#pragma unroll
            for (int j = 0; j < 8; ++j) {
                acc[j] = fmaf(x0, wv[j].x, acc[j]);
                acc[j] = fmaf(x1, wv[j].y, acc[j]);
                acc[j] = fmaf(x2, wv[j].z, acc[j]);
                acc[j] = fmaf(x3, wv[j].w, acc[j]);
            }
        }
    }

    // epilogue: bias + activation, store [g][b=lane][m0..m0+7] as 2 float4
    float v[8];
#pragma unroll
    for (int j = 0; j < 8; ++j) {
        float val = acc[j] + bias[m0 + j];
        if (g == 1)      val *= 0.03125f;                  // k / sqrt(M)
        else if (g == 3) val = __expf(val);                // exponential gate i
        else if (g >= 4) val = 1.f / (1.f + __expf(-val)); // sigmoid f, o
        v[j] = val;
    }
    float* outp = gates + (size_t)g * BATCH * MEM + (size_t)lane * MEM + m0;
    *(float4*)(outp + 0) = make_float4(v[0], v[1], v[2], v[3]);
    *(float4*)(outp + 4) = make_float4(v[4], v[5], v[6], v[7]);
}

// ---------------------------------------------------------------------------
// Kernel 2: n_t = f*n_prev + i*k ; denom[b] = max(n_t . q, 1)
// grid 64 (one block per batch) x 256
// ---------------------------------------------------------------------------
__global__ __launch_bounds__(256)
void nt_denom_kernel(const float* __restrict__ gates,
                     const float* __restrict__ n_prev,
                     float* __restrict__ n_out,
                     float* __restrict__ denom) {
    const int b = blockIdx.x;
    const int t = threadIdx.x;
    const float* q  = gates + 0 * BATCH * MEM + (size_t)b * MEM;
    const float* k  = gates + 1 * BATCH * MEM + (size_t)b * MEM;
    const float* ig = gates + 3 * BATCH * MEM + (size_t)b * MEM;
    const float* fg = gates + 4 * BATCH * MEM + (size_t)b * MEM;

    float part = 0.f;
#pragma unroll
    for (int j = 0; j < 4; ++j) {
        int m = t + j * 256;
        float nt = fg[m] * n_prev[(size_t)b * MEM + m] + ig[m] * k[m];
        n_out[(size_t)b * MEM + m] = nt;
        part += nt * q[m];
    }
#pragma unroll
    for (int off = 32; off; off >>= 1) part += __shfl_xor(part, off, 64);

    __shared__ float red[4];
    if ((t & 63) == 0) red[t >> 6] = part;
    __syncthreads();
    if (t == 0) denom[b] = fmaxf(red[0] + red[1] + red[2] + red[3], 1.0f);
}

// ---------------------------------------------------------------------------
// Kernel 3 (the roofline): per C-row (b,m):
//   C_t[b,m,:] = f[b,m]*C_prev[b,m,:] + (i*v)[b,m]*k[b,:]
//   h_t[b,m]   = o[b,m] * (C_t[b,m,:] . q[b,:]) / denom[b]
// 16 rows per block (same batch), one wave owns 4 rows; q,k staged once.
// Nontemporal 16B loads/stores: 537 MB single-use stream, keep it out of L2.
// grid 4096 x 256.
// ---------------------------------------------------------------------------
__global__ __launch_bounds__(256)
void update_kernel(const float* __restrict__ C_prev,
                   const float* __restrict__ gates,
                   const float* __restrict__ denom,
                   float* __restrict__ h_out,
                   float* __restrict__ C_out) {
    __shared__ f32x4 qs[MEM / 4];
    __shared__ f32x4 ks[MEM / 4];
    const int t    = threadIdx.x;
    const int row0 = blockIdx.x * 16;
    const int b    = row0 >> 10;

    qs[t] = ((const f32x4*)(gates + 0 * BATCH * MEM + (size_t)b * MEM))[t];
    ks[t] = ((const f32x4*)(gates + 1 * BATCH * MEM + (size_t)b * MEM))[t];
    __syncthreads();

    const int wave = __builtin_amdgcn_readfirstlane(t >> 6);
    const int lane = t & 63;
    const float inv_den = 1.0f / denom[b];

#pragma unroll
    for (int r = 0; r < 4; ++r) {
        const int row = row0 + wave * 4 + r;
        const int m   = row & 1023;

        const float fm = gates[4 * BATCH * MEM + (size_t)b * MEM + m];
        const float iv = gates[3 * BATCH * MEM + (size_t)b * MEM + m] *
                         gates[2 * BATCH * MEM + (size_t)b * MEM + m];
        const float om = gates[5 * BATCH * MEM + (size_t)b * MEM + m];

        const f32x4* cp = (const f32x4*)(C_prev + (size_t)row * MEM);
        f32x4*       co = (f32x4*)(C_out + (size_t)row * MEM);

        float acc = 0.f;
#pragma unroll
        for (int c = 0; c < 4; ++c) {
            int n4 = c * 64 + lane;
            f32x4 cv = __builtin_nontemporal_load(&cp[n4]);
            f32x4 kv = ks[n4];
            f32x4 qv = qs[n4];
            f32x4 ct;
            ct.x = fmaf(fm, cv.x, iv * kv.x);
            ct.y = fmaf(fm, cv.y, iv * kv.y);
            ct.z = fmaf(fm, cv.z, iv * kv.z);
            ct.w = fmaf(fm, cv.w, iv * kv.w);
            __builtin_nontemporal_store(ct, &co[n4]);
            acc = fmaf(ct.x, qv.x, acc);
            acc = fmaf(ct.y, qv.y, acc);
            acc = fmaf(ct.z, qv.z, acc);
            acc = fmaf(ct.w, qv.w, acc);
        }
#pragma unroll
        for (int off = 32; off; off >>= 1) acc += __shfl_xor(acc, off, 64);

        if (lane == 0) h_out[row] = om * acc * inv_den;
    }
}

// ---------------------------------------------------------------------------
extern "C" void kernel_launch(void* const* d_in, const int* in_sizes, int n_in,
                              void* d_out, int out_size, void* d_ws, size_t ws_size,
                              hipStream_t stream) {
    const float* x      = (const float*)d_in[0];
    const float* C_prev = (const float*)d_in[3];
    const float* n_prev = (const float*)d_in[4];
    const float* Wq = (const float*)d_in[6];  const float* bq = (const float*)d_in[7];
    const float* Wk = (const float*)d_in[8];  const float* bk = (const float*)d_in[9];
    const float* Wv = (const float*)d_in[10]; const float* bv = (const float*)d_in[11];
    const float* Wi = (const float*)d_in[12]; const float* bi = (const float*)d_in[13];
    const float* Wf = (const float*)d_in[14]; const float* bf = (const float*)d_in[15];
    const float* Wo = (const float*)d_in[16]; const float* bo = (const float*)d_in[17];

    float* h_out = (float*)d_out;                       // [64,1024]
    float* C_out = h_out + BATCH * MEM;                 // [64,1024,1024]
    float* n_out = C_out + (size_t)BATCH * MEM * MEM;   // [64,1024]

    float* gates = (float*)d_ws;                        // 6 * 64 * 1024 floats
    float* denom = gates + 6 * BATCH * MEM;             // 64 floats

    gates_kernel<<<192, 256, 0, stream>>>(x, Wq, bq, Wk, bk, Wv, bv,
                                          Wi, bi, Wf, bf, Wo, bo, gates);
    nt_denom_kernel<<<64, 256, 0, stream>>>(gates, n_prev, n_out, denom);
    update_kernel<<<4096, 256, 0, stream>>>(C_prev, gates, denom, h_out, C_out);
}